// Round 5
// baseline (135.949 us; speedup 1.0000x reference)
//
#include <hip/hip_runtime.h>

#define LOG2E 1.4426950408889634f
#define NEGBIG -3.0e38f

typedef float  f32x4  __attribute__((ext_vector_type(4)));
typedef float  f32x16 __attribute__((ext_vector_type(16)));
typedef short  bf16x8 __attribute__((ext_vector_type(8)));
typedef unsigned short u16x4 __attribute__((ext_vector_type(4)));
typedef int    i32x4  __attribute__((ext_vector_type(4)));
typedef unsigned int u32x2 __attribute__((ext_vector_type(2)));

__device__ __forceinline__ unsigned short f2bf(float f) {
  union { float f; unsigned u; } v; v.f = f;
  unsigned r = v.u + 0x7FFFu + ((v.u >> 16) & 1u);
  return (unsigned short)(r >> 16);
}

__device__ __forceinline__ unsigned cvtpk(float a, float b) {
  unsigned r;
  asm("v_cvt_pk_bf16_f32 %0, %1, %2" : "=v"(r) : "v"(a), "v"(b));
  return r;
}

__device__ __forceinline__ bf16x8 load_cvt8(const float* p) {
  f32x4 a = *(const f32x4*)p;
  f32x4 b = *(const f32x4*)(p + 4);
  bf16x8 r;
  r[0]=(short)f2bf(a[0]); r[1]=(short)f2bf(a[1]); r[2]=(short)f2bf(a[2]); r[3]=(short)f2bf(a[3]);
  r[4]=(short)f2bf(b[0]); r[5]=(short)f2bf(b[1]); r[6]=(short)f2bf(b[2]); r[7]=(short)f2bf(b[3]);
  return r;
}

// ---------------------------------------------------------------------------
// Kernel 1: QKV projection (unchanged, known-good).
// ---------------------------------------------------------------------------
__global__ __launch_bounds__(256) void qkv_kernel(
    const float* __restrict__ x,
    const float* __restrict__ wq, const float* __restrict__ wk, const float* __restrict__ wv,
    unsigned short* __restrict__ Qo, unsigned short* __restrict__ Ko,
    unsigned short* __restrict__ Vto)
{
  const int mode = blockIdx.y;
  const int n0   = blockIdx.x * 64;
  const int b    = n0 >> 11;
  const int nl0  = n0 & 2047;
  const int wave = threadIdx.x >> 6;
  const int lane = threadIdx.x & 63;
  const int li = lane & 15, qt = lane >> 4;

  f32x4 acc[4][4];
#pragma unroll
  for (int i = 0; i < 4; i++)
#pragma unroll
    for (int j = 0; j < 4; j++) acc[i][j] = (f32x4)0.0f;

  if (mode < 2) {
    const float* w = mode ? wk : wq;
    unsigned short* out = mode ? Ko : Qo;
    const float osc = mode ? 1.0f : (1.4426950408889634f / 5.656854249492381f);
#pragma unroll
    for (int ks = 0; ks < 8; ks++) {
      bf16x8 af[4], bfr[4];
#pragma unroll
      for (int dm = 0; dm < 4; dm++)
        af[dm] = load_cvt8(w + (size_t)(wave*64 + dm*16 + li)*256 + ks*32 + qt*8);
#pragma unroll
      for (int nf = 0; nf < 4; nf++)
        bfr[nf] = load_cvt8(x + (size_t)(n0 + nf*16 + li)*256 + ks*32 + qt*8);
#pragma unroll
      for (int dm = 0; dm < 4; dm++)
#pragma unroll
        for (int nf = 0; nf < 4; nf++)
          acc[dm][nf] = __builtin_amdgcn_mfma_f32_16x16x32_bf16(af[dm], bfr[nf], acc[dm][nf], 0, 0, 0);
    }
#pragma unroll
    for (int dm = 0; dm < 4; dm++) {
      const int dbase = wave*64 + dm*16 + qt*4;
      const int h = dbase >> 5, dk = dbase & 31;
#pragma unroll
      for (int nf = 0; nf < 4; nf++) {
        const int nl = nl0 + nf*16 + li;
        u16x4 o;
#pragma unroll
        for (int r = 0; r < 4; r++) o[r] = f2bf(acc[dm][nf][r] * osc);
        *(u16x4*)(out + ((size_t)(b*8 + h)*2048 + nl)*32 + dk) = o;
      }
    }
  } else {
#pragma unroll
    for (int ks = 0; ks < 8; ks++) {
      bf16x8 af[4], bfr[4];
#pragma unroll
      for (int nm = 0; nm < 4; nm++)
        af[nm] = load_cvt8(x + (size_t)(n0 + nm*16 + li)*256 + ks*32 + qt*8);
#pragma unroll
      for (int df = 0; df < 4; df++)
        bfr[df] = load_cvt8(wv + (size_t)(wave*64 + df*16 + li)*256 + ks*32 + qt*8);
#pragma unroll
      for (int nm = 0; nm < 4; nm++)
#pragma unroll
        for (int df = 0; df < 4; df++)
          acc[nm][df] = __builtin_amdgcn_mfma_f32_16x16x32_bf16(af[nm], bfr[df], acc[nm][df], 0, 0, 0);
    }
#pragma unroll
    for (int nm = 0; nm < 4; nm++) {
      const int nl = nl0 + nm*16 + qt*4;
#pragma unroll
      for (int df = 0; df < 4; df++) {
        const int d = wave*64 + df*16 + li;
        const int h = d >> 5, dk = d & 31;
        u16x4 o;
#pragma unroll
        for (int r = 0; r < 4; r++) o[r] = f2bf(acc[nm][df][r]);
        *(u16x4*)(Vto + ((size_t)(b*8 + h)*32 + dk)*2048 + nl) = o;
      }
    }
  }
}

// ---------------------------------------------------------------------------
// Kernel 2: fused flash attention, 32x32x16 MFMA, q-tile 32, 8 waves = 8
// heads. S^T = K*Q^T (lane = one q-column). Streaming softmax (no online max,
// exp2 domain bounded). P -> PV B-operand via cvt_pk_bf16 + permlane32_swap.
// edge/mask staged in LDS, 128 keys per phase, double-buffered; ALL sync via
// __syncthreads() (full drain; proven-deterministic). Prefetch issued a full
// phase ahead so the vmcnt drain at the barrier is cheap.
// ---------------------------------------------------------------------------
__global__ __launch_bounds__(512, 2) void attn_kernel(
    const unsigned short* __restrict__ Qg,   // [B][H][N][32]
    const unsigned short* __restrict__ Kg,   // [B][H][N][32]
    const unsigned short* __restrict__ Vt,   // [B][H][32][N]
    const float* __restrict__ edge,          // [B][N][N]
    const int*   __restrict__ mask,          // [B][N][N]
    unsigned short* __restrict__ Og)         // [B][N][256]
{
  __shared__ __attribute__((aligned(16))) float me_s[2][4096];  // 2 buf x 2 tiles

  const int bid = blockIdx.x;
  const int b  = (bid >> 1) & 3;                  // XCD pair per batch
  const int qi = ((bid >> 3) << 1) | (bid & 1);   // 0..63
  const int q0 = qi * 32;
  const int tid  = threadIdx.x;
  const int wave = tid >> 6;                 // = head
  const int lane = tid & 63;
  const int ql = lane & 31, hi = lane >> 5;
  const int h = wave;

  const unsigned short* qbase = Qg + ((size_t)(b*8 + h)*2048 + q0)*32;
  const unsigned short* kbase = Kg + ((size_t)(b*8 + h)*2048)*32;
  const unsigned short* vbase = Vt + ((size_t)(b*8 + h)*32)*2048;

  // staging map: thread t -> (q = t>>4, keys (t&15)*4 .. +3) per tile
  const int q_s = tid >> 4;
  const int k4  = (tid & 15) * 4;
  const float* eaddr = edge + ((size_t)b*2048 + q0 + q_s)*2048 + k4;
  const int*   maddr = mask + ((size_t)b*2048 + q0 + q_s)*2048 + k4;
  // tile-local write index: cell=(sm*4+rg)*64 + hi*32 + (q^sw), sw=((rg<<1)|hi)^(sm<<2)
  const int ssm = k4 >> 5, srg = (k4 >> 3) & 3, shi = (k4 >> 2) & 1;
  const int ssw = ((srg << 1) | shi) ^ (ssm << 2);
  const int widx = ((ssm*4 + srg)*64 + shi*32 + (q_s ^ ssw)) * 4;
  // tile-local C-in read indices per (sm, rg)
  int rix0[4], rix1[4];
#pragma unroll
  for (int rg = 0; rg < 4; rg++) {
    rix0[rg] = ((rg)*64   + hi*32 + (ql ^ (((rg<<1)|hi)    ))) * 4;
    rix1[rg] = ((4+rg)*64 + hi*32 + (ql ^ (((rg<<1)|hi) ^ 4))) * 4;
  }

  // Q B-fragments (const): col = q0+ql, k = step*16 + hi*8 + j
  const bf16x8 qf0 = *(const bf16x8*)(qbase + (size_t)ql*32 +  0 + hi*8);
  const bf16x8 qf1 = *(const bf16x8*)(qbase + (size_t)ql*32 + 16 + hi*8);

  { // stage phase 0 (tiles 0 and 1)
    f32x4 e0 = *(const f32x4*)eaddr;
    i32x4 m0 = *(const i32x4*)maddr;
    f32x4 e1 = *(const f32x4*)(eaddr + 64);
    i32x4 m1 = *(const i32x4*)(maddr + 64);
    f32x4 v0, v1;
#pragma unroll
    for (int r = 0; r < 4; r++) v0[r] = m0[r] ? e0[r]*LOG2E : NEGBIG;
#pragma unroll
    for (int r = 0; r < 4; r++) v1[r] = m1[r] ? e1[r]*LOG2E : NEGBIG;
    *(f32x4*)&me_s[0][widx] = v0;
    *(f32x4*)&me_s[0][2048 + widx] = v1;
  }
  __syncthreads();

  // preload K tile 0: frag i = sm*2+step
  bf16x8 kf_a[4], kf_b[4];
#pragma unroll
  for (int i = 0; i < 4; i++)
    kf_a[i] = *(const bf16x8*)(kbase + (size_t)((i>>1)*32 + ql)*32 + (i&1)*16 + hi*8);

  float lsum = 0.f;
  f32x16 oacc = (f32x16)0.0f;

  union CU { f32x16 v; f32x4 q[4]; };

#define PV_KS(SV, HALF, VA)                                                   \
  {                                                                           \
    unsigned a0 = cvtpk(SV[(HALF)*8+0], SV[(HALF)*8+1]);                      \
    unsigned a1 = cvtpk(SV[(HALF)*8+2], SV[(HALF)*8+3]);                      \
    unsigned b0 = cvtpk(SV[(HALF)*8+4], SV[(HALF)*8+5]);                      \
    unsigned b1 = cvtpk(SV[(HALF)*8+6], SV[(HALF)*8+7]);                      \
    u32x2 p0 = __builtin_amdgcn_permlane32_swap(a0, b0, false, false);        \
    u32x2 p1 = __builtin_amdgcn_permlane32_swap(a1, b1, false, false);        \
    i32x4 pw4;                                                                \
    pw4[0] = (int)p0[0]; pw4[1] = (int)p1[0];                                 \
    pw4[2] = (int)p0[1]; pw4[3] = (int)p1[1];                                 \
    const bf16x8 pf = __builtin_bit_cast(bf16x8, pw4);                        \
    oacc = __builtin_amdgcn_mfma_f32_32x32x16_bf16(VA, pf, oacc, 0, 0, 0);    \
  }

  // One 64-key sub-step: prefetch K(next tile) into KN, compute on KC.
#define SUBSTEP(K0, KC, KN, CB)                                               \
  {                                                                           \
    const int knK = ((K0) + 64) & 2047;                                       \
    _Pragma("unroll")                                                         \
    for (int i = 0; i < 4; i++)                                               \
      KN[i] = *(const bf16x8*)(kbase + (size_t)(knK + (i>>1)*32 + ql)*32 + (i&1)*16 + hi*8); \
    const bf16x8 vA0 = *(const bf16x8*)(vbase + (size_t)ql*2048 + (K0) +  0 + hi*8); \
    const bf16x8 vA1 = *(const bf16x8*)(vbase + (size_t)ql*2048 + (K0) + 16 + hi*8); \
    const bf16x8 vA2 = *(const bf16x8*)(vbase + (size_t)ql*2048 + (K0) + 32 + hi*8); \
    const bf16x8 vA3 = *(const bf16x8*)(vbase + (size_t)ql*2048 + (K0) + 48 + hi*8); \
    CU c0, c1;                                                                \
    _Pragma("unroll")                                                         \
    for (int rg = 0; rg < 4; rg++) c0.q[rg] = *(const f32x4*)((CB) + rix0[rg]); \
    _Pragma("unroll")                                                         \
    for (int rg = 0; rg < 4; rg++) c1.q[rg] = *(const f32x4*)((CB) + rix1[rg]); \
    f32x16 s0 = __builtin_amdgcn_mfma_f32_32x32x16_bf16(KC[0], qf0, c0.v, 0, 0, 0); \
    s0 = __builtin_amdgcn_mfma_f32_32x32x16_bf16(KC[1], qf1, s0, 0, 0, 0);    \
    f32x16 s1 = __builtin_amdgcn_mfma_f32_32x32x16_bf16(KC[2], qf0, c1.v, 0, 0, 0); \
    s1 = __builtin_amdgcn_mfma_f32_32x32x16_bf16(KC[3], qf1, s1, 0, 0, 0);    \
    _Pragma("unroll")                                                         \
    for (int i = 0; i < 16; i++) s0[i] = __builtin_amdgcn_exp2f(s0[i]);       \
    _Pragma("unroll")                                                         \
    for (int i = 0; i < 16; i++) s1[i] = __builtin_amdgcn_exp2f(s1[i]);       \
    {                                                                         \
      float r0 = 0.f, r1 = 0.f, r2 = 0.f, r3 = 0.f;                           \
      _Pragma("unroll")                                                       \
      for (int i = 0; i < 4; i++) {                                           \
        r0 += s0[4*i]; r1 += s0[4*i+1]; r2 += s0[4*i+2]; r3 += s0[4*i+3];     \
        r0 += s1[4*i]; r1 += s1[4*i+1]; r2 += s1[4*i+2]; r3 += s1[4*i+3];     \
      }                                                                       \
      lsum += (r0 + r1) + (r2 + r3);                                          \
    }                                                                         \
    PV_KS(s0, 0, vA0)                                                         \
    PV_KS(s0, 1, vA1)                                                         \
    PV_KS(s1, 0, vA2)                                                         \
    PV_KS(s1, 1, vA3)                                                         \
  }

  for (int p = 0; p < 16; ++p) {
    const int buf = p & 1;
    const int k0 = p * 128;
    const bool st = (p < 15);
    f32x4 se0, se1; i32x4 sm0, sm1;
    if (st) { // prefetch next phase's edge/mask (full phase of latency cover)
      se0 = *(const f32x4*)(eaddr + k0 + 128);
      sm0 = *(const i32x4*)(maddr + k0 + 128);
      se1 = *(const f32x4*)(eaddr + k0 + 192);
      sm1 = *(const i32x4*)(maddr + k0 + 192);
    }
    SUBSTEP(k0,      kf_a, kf_b, &me_s[buf][0])
    SUBSTEP(k0 + 64, kf_b, kf_a, &me_s[buf][2048])
    if (st) {
      f32x4 v0, v1;
#pragma unroll
      for (int r = 0; r < 4; r++) v0[r] = sm0[r] ? se0[r]*LOG2E : NEGBIG;
#pragma unroll
      for (int r = 0; r < 4; r++) v1[r] = sm1[r] ? se1[r]*LOG2E : NEGBIG;
      *(f32x4*)&me_s[buf ^ 1][widx] = v0;
      *(f32x4*)&me_s[buf ^ 1][2048 + widx] = v1;
    }
    __syncthreads();
  }
#undef SUBSTEP
#undef PV_KS

  const float ltot = lsum + __shfl_xor(lsum, 32);
  const float rl = 1.0f / ltot;
  // O^T: lane holds col q = ql, rows d = (r&3) + 8*rg + 4*hi
#pragma unroll
  for (int rg = 0; rg < 4; rg++) {
    u16x4 o;
#pragma unroll
    for (int r = 0; r < 4; r++) o[r] = f2bf(oacc[rg*4 + r] * rl);
    *(u16x4*)(Og + ((size_t)(b*2048 + q0 + ql))*256 + h*32 + rg*8 + hi*4) = o;
  }
}

// ---------------------------------------------------------------------------
// Kernel 3: output projection (unchanged, known-good).
// ---------------------------------------------------------------------------
__global__ __launch_bounds__(256) void proj_kernel(
    const unsigned short* __restrict__ O,    // [8192][256] bf16
    const float* __restrict__ wo, const float* __restrict__ bo,
    float* __restrict__ Y)                   // [8192][256] f32
{
  const int n0   = blockIdx.x * 64;
  const int wave = threadIdx.x >> 6;
  const int lane = threadIdx.x & 63;
  const int li = lane & 15, qt = lane >> 4;

  f32x4 acc[4][4];
#pragma unroll
  for (int i = 0; i < 4; i++)
#pragma unroll
    for (int j = 0; j < 4; j++) acc[i][j] = (f32x4)0.0f;

#pragma unroll
  for (int ks = 0; ks < 8; ks++) {
    bf16x8 af[4], bfr[4];
#pragma unroll
    for (int dm = 0; dm < 4; dm++)
      af[dm] = load_cvt8(wo + (size_t)(wave*64 + dm*16 + li)*256 + ks*32 + qt*8);
#pragma unroll
    for (int nf = 0; nf < 4; nf++)
      bfr[nf] = *(const bf16x8*)(O + (size_t)(n0 + nf*16 + li)*256 + ks*32 + qt*8);
#pragma unroll
    for (int dm = 0; dm < 4; dm++)
#pragma unroll
      for (int nf = 0; nf < 4; nf++)
        acc[dm][nf] = __builtin_amdgcn_mfma_f32_16x16x32_bf16(af[dm], bfr[nf], acc[dm][nf], 0, 0, 0);
  }

#pragma unroll
  for (int dm = 0; dm < 4; dm++) {
    const int d0 = wave*64 + dm*16 + qt*4;
    const f32x4 bo4 = *(const f32x4*)(bo + d0);
#pragma unroll
    for (int nf = 0; nf < 4; nf++) {
      const int n = n0 + nf*16 + li;
      f32x4 y = acc[dm][nf] + bo4;
      *(f32x4*)(Y + (size_t)n*256 + d0) = y;
    }
  }
}

// ---------------------------------------------------------------------------
extern "C" void kernel_launch(void* const* d_in, const int* in_sizes, int n_in,
                              void* d_out, int out_size, void* d_ws, size_t ws_size,
                              hipStream_t stream) {
  const float* x  = (const float*)d_in[0];
  const float* ew = (const float*)d_in[1];
  const int*   mk = (const int*)d_in[2];
  const float* wq = (const float*)d_in[3];
  const float* wk = (const float*)d_in[4];
  const float* wv = (const float*)d_in[5];
  const float* wo = (const float*)d_in[6];
  const float* bo = (const float*)d_in[7];
  float* y = (float*)d_out;

  unsigned short* Q  = (unsigned short*)d_ws;       // [4][8][2048][32] bf16
  unsigned short* K  = Q  + 2097152;
  unsigned short* Vt = K  + 2097152;                // [4][8][32][2048] bf16
  unsigned short* O  = Vt + 2097152;                // [4][2048][256]  bf16

  qkv_kernel<<<dim3(128, 3), 256, 0, stream>>>(x, wq, wk, wv, Q, K, Vt);
  attn_kernel<<<256, 512, 0, stream>>>(Q, K, Vt, ew, mk, O);
  proj_kernel<<<128, 256, 0, stream>>>(O, wo, bo, y);
}